// Round 6
// baseline (219.396 us; speedup 1.0000x reference)
//
#include <hip/hip_runtime.h>
#include <hip/hip_fp16.h>
#include <cstdint>
#include <cstddef>

#define B_ 512
#define T_ 256
#define N_ 128
#define H_ 64
#define G_ 256  // 4H

typedef __attribute__((ext_vector_type(8))) short short8;
typedef __attribute__((ext_vector_type(4))) float f32x4;
typedef _Float16 half2_t __attribute__((ext_vector_type(2)));

static __device__ __forceinline__ float bf2f(unsigned short u) {
    union { unsigned int i; float f; } v;
    v.i = ((unsigned int)u) << 16;
    return v.f;
}
static __device__ __forceinline__ unsigned short f2bf(float f) {
    union { float f; unsigned int i; } v;
    v.f = f;
    unsigned int x = v.i;
    return (unsigned short)((x + 0x7fffu + ((x >> 16) & 1u)) >> 16);  // RNE
}
static __device__ __forceinline__ half2_t u2h2(unsigned int u) {
    union { unsigned int u; half2_t h; } v; v.u = u; return v.h;
}
static __device__ __forceinline__ unsigned int h2u(half2_t h) {
    union { half2_t h; unsigned int u; } v; v.h = h; return v.u;
}

// ---------------------------------------------------------------------------
// K1+K2 fused: per-batch block (512 blocks, 256 threads).
// Phase A: a[n] = softmax_n( sum_t x[b][t][n]*aw2[t] ); x ALSO staged to LDS
//          as bf16 (single global x pass: 268->201 MB total traffic).
// Phase B: iw = a*x (from LDS) -> d_out; gatesx = wx@W_ih^T + bias (f16) -> ws
// LDS 146.4 KB -> 1 block/CU.
// ---------------------------------------------------------------------------
__global__ __launch_bounds__(256) void k_awgemm(const float* __restrict__ x,
                                                const float* __restrict__ attn_w,
                                                const float* __restrict__ W_ih,
                                                const float* __restrict__ b_ih,
                                                const float* __restrict__ b_hh,
                                                float* __restrict__ iw,
                                                _Float16* __restrict__ gatesx) {
    __shared__ __align__(16) unsigned short Wl[G_][136];  // bf16 W_ih, padded
    __shared__ __align__(16) unsigned short Xl[T_][N_];   // bf16 x tile (65.5 KB)
    __shared__ __align__(16) unsigned short Al[32][136];  // bf16 wx subtile (overlaid: red)
    __shared__ float bias[G_];
    __shared__ float aw_s[T_];
    __shared__ float a_s[N_];
    __shared__ float wred[4];
    const int tid = threadIdx.x;
    const int b = blockIdx.x;

    for (int q = tid; q < G_ * 32; q += 256) {
        int r = q >> 5, c4 = (q & 31) << 2;
        float4 v = *(const float4*)(W_ih + r * N_ + c4);
        Wl[r][c4 + 0] = f2bf(v.x); Wl[r][c4 + 1] = f2bf(v.y);
        Wl[r][c4 + 2] = f2bf(v.z); Wl[r][c4 + 3] = f2bf(v.w);
    }
    bias[tid] = b_ih[tid] + b_hh[tid];
    aw_s[tid] = attn_w[2 * H_ + tid];
    __syncthreads();

    // ---- Phase A: attention dot + softmax; stage x->LDS bf16 on the way ----
    float (*red)[128] = (float(*)[128])&Al[0][0];
    const int n0 = (tid & 31) << 2;
    const int tg = tid >> 5;
    const float* xb = x + (size_t)b * (T_ * N_);
    {
        float p0 = 0.f, p1 = 0.f, p2 = 0.f, p3 = 0.f;
        for (int t = tg; t < T_; t += 8) {
            float4 v = *(const float4*)(xb + t * N_ + n0);
            float w = aw_s[t];
            p0 += v.x * w; p1 += v.y * w; p2 += v.z * w; p3 += v.w * w;
            Xl[t][n0 + 0] = f2bf(v.x); Xl[t][n0 + 1] = f2bf(v.y);
            Xl[t][n0 + 2] = f2bf(v.z); Xl[t][n0 + 3] = f2bf(v.w);
        }
        red[tg][n0 + 0] = p0; red[tg][n0 + 1] = p1;
        red[tg][n0 + 2] = p2; red[tg][n0 + 3] = p3;
    }
    __syncthreads();
    {
        float s = 0.f;
        if (tid < 128) {
            #pragma unroll
            for (int g = 0; g < 8; ++g) s += red[g][tid];
        }
        float m = (tid < 128) ? s : -1e30f;
        #pragma unroll
        for (int d = 1; d < 64; d <<= 1) m = fmaxf(m, __shfl_xor(m, d));
        if ((tid & 63) == 0) wred[tid >> 6] = m;
        __syncthreads();
        m = fmaxf(wred[0], wred[1]);
        __syncthreads();
        float e = (tid < 128) ? __expf(s - m) : 0.f;
        float z = e;
        #pragma unroll
        for (int d = 1; d < 64; d <<= 1) z += __shfl_xor(z, d);
        if ((tid & 63) == 0) wred[tid >> 6] = z;
        __syncthreads();
        z = wred[0] + wred[1];
        if (tid < 128) a_s[tid] = e / z;
    }
    __syncthreads();   // a_s ready; red dead -> Al reusable

    // ---- Phase B: weighting (from LDS x) + MFMA GEMM ----
    const int lane = tid & 63;
    const int lr = lane & 15;
    const int lk = (lane >> 4) << 3;
    const int gc0 = (tid >> 6) << 6;
    const int orow = (lane >> 4) << 2;

    for (int st = 0; st < 8; ++st) {
        const int r0 = b * T_ + st * 32;
        __syncthreads();
        for (int q = tid; q < 32 * 32; q += 256) {
            int r = q >> 5, c4 = (q & 31) << 2;
            ushort4 xv = *(const ushort4*)(&Xl[st * 32 + r][c4]);
            float4 w;
            w.x = a_s[c4 + 0] * bf2f(xv.x); w.y = a_s[c4 + 1] * bf2f(xv.y);
            w.z = a_s[c4 + 2] * bf2f(xv.z); w.w = a_s[c4 + 3] * bf2f(xv.w);
            *(float4*)(iw + (size_t)(r0 + r) * N_ + c4) = w;   // output 0
            Al[r][c4 + 0] = f2bf(w.x); Al[r][c4 + 1] = f2bf(w.y);
            Al[r][c4 + 2] = f2bf(w.z); Al[r][c4 + 3] = f2bf(w.w);
        }
        __syncthreads();

        f32x4 acc[2][4];
        #pragma unroll
        for (int mt = 0; mt < 2; ++mt)
            #pragma unroll
            for (int nt = 0; nt < 4; ++nt)
                acc[mt][nt] = (f32x4){0.f, 0.f, 0.f, 0.f};

        #pragma unroll
        for (int kk = 0; kk < N_; kk += 32) {
            short8 af0 = *(const short8*)(&Al[lr][kk + lk]);
            short8 af1 = *(const short8*)(&Al[16 + lr][kk + lk]);
            #pragma unroll
            for (int nt = 0; nt < 4; ++nt) {
                short8 bfv = *(const short8*)(&Wl[gc0 + nt * 16 + lr][kk + lk]);
                acc[0][nt] = __builtin_amdgcn_mfma_f32_16x16x32_bf16(af0, bfv, acc[0][nt], 0, 0, 0);
                acc[1][nt] = __builtin_amdgcn_mfma_f32_16x16x32_bf16(af1, bfv, acc[1][nt], 0, 0, 0);
            }
        }
        #pragma unroll
        for (int mt = 0; mt < 2; ++mt) {
            #pragma unroll
            for (int nt = 0; nt < 4; ++nt) {
                int col = gc0 + nt * 16 + lr;
                float bs = bias[col];
                #pragma unroll
                for (int rg = 0; rg < 4; ++rg) {
                    int rr = r0 + mt * 16 + orow + rg;
                    gatesx[(size_t)rr * G_ + col] = (_Float16)(acc[mt][nt][rg] + bs);
                }
            }
        }
    }
}

// ---------------------------------------------------------------------------
// K3: LSTM recurrence, SINGLE-WAVE blocks (64 thr), 512 blocks.
// Round-5 lesson: 1327 cy/step; the 2 barriers/step each force
// s_waitcnt vmcnt(0) (enc-store + prefetch drain ON the chain) + 4-wave skew.
// This version: thread j owns CELL j -- all 4 gate rows in 128 packed-f16
// VGPRs; h broadcast via uniform ds_read_b128; cell math lane-local.
// ZERO barriers (single wave; LDS ordering via compiler lgkmcnt).
// Chain/step ~ 120 (LDS bcast) + 256 (128 fdot2 issue) + ~60 (trans) cy.
// ---------------------------------------------------------------------------
__global__ __attribute__((amdgpu_flat_work_group_size(64, 64)))
__attribute__((amdgpu_waves_per_eu(1, 2)))
void k_rnn4(const _Float16* __restrict__ gatesx,
            const float* __restrict__ W_hh,
            float* __restrict__ enc) {
    __shared__ __align__(16) _Float16 hb[H_];   // h_t, f16, 128 B
    const int j = threadIdx.x;   // cell index
    const int b = blockIdx.x;

    // 4 gate rows (i,f,g,o) of W_hh for cell j -> 4 x 32 packed half2
    half2_t w2[4][32];
    #pragma unroll
    for (int g = 0; g < 4; ++g) {
        const float* src = W_hh + (size_t)(g * H_ + j) * H_;
        #pragma unroll
        for (int q = 0; q < 16; ++q) {
            float4 v = *(const float4*)(src + q * 4);
            w2[g][2 * q + 0] = (half2_t){(_Float16)v.x, (_Float16)v.y};
            w2[g][2 * q + 1] = (half2_t){(_Float16)v.z, (_Float16)v.w};
        }
    }
    // pin weights in VGPRs (stop the scheduler from sinking the loads)
    #pragma unroll
    for (int g = 0; g < 4; ++g) {
        #pragma unroll
        for (int k = 0; k < 32; ++k) {
            unsigned int u = h2u(w2[g][k]);
            asm volatile("" : "+v"(u));
            w2[g][k] = u2h2(u);
        }
    }

    if (j < 32) ((unsigned int*)hb)[j] = 0u;   // h_{-1} = 0
    __syncthreads();                            // one-time; cheap for 1 wave
    float c = 0.f;

    const _Float16* gx = gatesx + (size_t)b * T_ * G_ + j;
    float g0 = (float)gx[0];
    float g1 = (float)gx[64];
    float g2 = (float)gx[128];
    float g3 = (float)gx[192];

    for (int t = 0; t < T_; ++t) {
        // prefetch next step's 4 gate inputs (coalesced 128B each)
        const _Float16* gp = gx + (size_t)(t + 1 < T_ ? t + 1 : t) * G_;
        _Float16 n0 = gp[0], n1 = gp[64], n2 = gp[128], n3 = gp[192];

        // h broadcast: 8 uniform-address b128 reads (conflict-free broadcast)
        const uint4* hv = (const uint4*)hb;
        float a0 = g0, a1 = g1, a2 = g2, a3 = g3;
        #pragma unroll
        for (int q = 0; q < 8; ++q) {
            uint4 ch = hv[q];
            a0 = __builtin_amdgcn_fdot2(w2[0][4 * q + 0], u2h2(ch.x), a0, false);
            a1 = __builtin_amdgcn_fdot2(w2[1][4 * q + 0], u2h2(ch.x), a1, false);
            a2 = __builtin_amdgcn_fdot2(w2[2][4 * q + 0], u2h2(ch.x), a2, false);
            a3 = __builtin_amdgcn_fdot2(w2[3][4 * q + 0], u2h2(ch.x), a3, false);
            a0 = __builtin_amdgcn_fdot2(w2[0][4 * q + 1], u2h2(ch.y), a0, false);
            a1 = __builtin_amdgcn_fdot2(w2[1][4 * q + 1], u2h2(ch.y), a1, false);
            a2 = __builtin_amdgcn_fdot2(w2[2][4 * q + 1], u2h2(ch.y), a2, false);
            a3 = __builtin_amdgcn_fdot2(w2[3][4 * q + 1], u2h2(ch.y), a3, false);
            a0 = __builtin_amdgcn_fdot2(w2[0][4 * q + 2], u2h2(ch.z), a0, false);
            a1 = __builtin_amdgcn_fdot2(w2[1][4 * q + 2], u2h2(ch.z), a1, false);
            a2 = __builtin_amdgcn_fdot2(w2[2][4 * q + 2], u2h2(ch.z), a2, false);
            a3 = __builtin_amdgcn_fdot2(w2[3][4 * q + 2], u2h2(ch.z), a3, false);
            a0 = __builtin_amdgcn_fdot2(w2[0][4 * q + 3], u2h2(ch.w), a0, false);
            a1 = __builtin_amdgcn_fdot2(w2[1][4 * q + 3], u2h2(ch.w), a1, false);
            a2 = __builtin_amdgcn_fdot2(w2[2][4 * q + 3], u2h2(ch.w), a2, false);
            a3 = __builtin_amdgcn_fdot2(w2[3][4 * q + 3], u2h2(ch.w), a3, false);
        }

        // cell math, fully lane-local (gate order i,f,g,o)
        float si = 1.f / (1.f + __expf(-a0));
        float sf = 1.f / (1.f + __expf(-a1));
        float tg = 1.f - 2.f / (__expf(2.f * a2) + 1.f);   // tanh(g)
        float so = 1.f / (1.f + __expf(-a3));
        c = sf * c + si * tg;
        float tc = 1.f - 2.f / (__expf(2.f * c) + 1.f);    // tanh(c)
        float h = so * tc;

        hb[j] = (_Float16)h;   // next iter's reads wait on lgkmcnt (same wave)
        enc[((size_t)b * T_ + t) * H_ + j] = h;
        g0 = (float)n0; g1 = (float)n1; g2 = (float)n2; g3 = (float)n3;
    }
}

extern "C" void kernel_launch(void* const* d_in, const int* in_sizes, int n_in,
                              void* d_out, int out_size, void* d_ws, size_t ws_size,
                              hipStream_t stream) {
    if (n_in < 7 || in_sizes[0] != B_ * T_ * N_) return;

    const float* x    = (const float*)d_in[0];
    const float* aw   = (const float*)d_in[1];
    // d_in[2] (attn_b) provably cancels in the softmax — unused.
    const float* W_ih = (const float*)d_in[3];
    const float* W_hh = (const float*)d_in[4];
    const float* b_ih = (const float*)d_in[5];
    const float* b_hh = (const float*)d_in[6];

    float* iwp = (float*)d_out;                          // (B,T,N) f32
    float* enc = (float*)d_out + (size_t)B_ * T_ * N_;   // (B,T,H) f32

    _Float16* gatesx = (_Float16*)d_ws;                  // B*T*G f16
    size_t need = (size_t)B_ * T_ * G_ * sizeof(_Float16);
    if (ws_size < need) return;  // fail loudly rather than corrupt

    hipLaunchKernelGGL(k_awgemm, dim3(B_), dim3(256), 0, stream,
                       x, aw, W_ih, b_ih, b_hh, iwp, gatesx);
    hipLaunchKernelGGL(k_rnn4, dim3(B_), dim3(64), 0, stream, gatesx, W_hh, enc);
}

// Round 7
// 208.506 us; speedup vs baseline: 1.0522x; 1.0522x over previous
//
#include <hip/hip_runtime.h>
#include <hip/hip_fp16.h>
#include <cstdint>
#include <cstddef>

#define B_ 512
#define T_ 256
#define N_ 128
#define H_ 64
#define G_ 256  // 4H

typedef __attribute__((ext_vector_type(8))) short short8;
typedef __attribute__((ext_vector_type(4))) float f32x4;
typedef _Float16 half2_t __attribute__((ext_vector_type(2)));

static __device__ __forceinline__ unsigned short f2bf(float f) {
    union { float f; unsigned int i; } v;
    v.f = f;
    unsigned int x = v.i;
    return (unsigned short)((x + 0x7fffu + ((x >> 16) & 1u)) >> 16);  // RNE
}
static __device__ __forceinline__ half2_t u2h2(unsigned int u) {
    union { unsigned int u; half2_t h; } v; v.u = u; return v.h;
}

// ---------------------------------------------------------------------------
// K0: pack W_hh (f32 [4H][H]) -> wpack uint4 [4][8][64]: wpack[g][q][j] =
// half2x4 of W_hh[g*64+j][8q..8q+7].  Exactly the per-lane order k_rnn5 loads.
// ---------------------------------------------------------------------------
__global__ __launch_bounds__(256) void k_wpack(const float* __restrict__ W_hh,
                                               uint4* __restrict__ wpack) {
    int idx = blockIdx.x * 256 + threadIdx.x;   // 2048 entries
    if (idx >= 2048) return;
    int g = idx >> 9, q = (idx >> 6) & 7, j = idx & 63;
    const float* src = W_hh + ((size_t)(g * H_ + j)) * H_ + q * 8;
    float4 a = *(const float4*)(src);
    float4 b = *(const float4*)(src + 4);
    union { uint4 u; half2_t h[4]; } pk;
    pk.h[0] = (half2_t){(_Float16)a.x, (_Float16)a.y};
    pk.h[1] = (half2_t){(_Float16)a.z, (_Float16)a.w};
    pk.h[2] = (half2_t){(_Float16)b.x, (_Float16)b.y};
    pk.h[3] = (half2_t){(_Float16)b.z, (_Float16)b.w};
    wpack[idx] = pk.u;
}

// ---------------------------------------------------------------------------
// K1+K2 fused (round-5 form: 80.9 KB LDS, 2 blocks/CU — the round-6 x-staging
// variant cost occupancy and regressed 43->56us; reverted).
// Phase A: a[n] = softmax_n( sum_t x[b][t][n]*aw2[t] )
// Phase B: iw = a*x (f32, exact) -> d_out; gatesx -> ws as f16 in
//          [b][t][cell][gate i,f,g,o] quads (one 8B load/step in k_rnn5).
// ---------------------------------------------------------------------------
__global__ __launch_bounds__(256) void k_awgemm(const float* __restrict__ x,
                                                const float* __restrict__ attn_w,
                                                const float* __restrict__ W_ih,
                                                const float* __restrict__ b_ih,
                                                const float* __restrict__ b_hh,
                                                float* __restrict__ iw,
                                                _Float16* __restrict__ gatesx) {
    __shared__ __align__(16) unsigned short Wl[G_][136];  // bf16 W_ih, padded
    __shared__ __align__(16) unsigned short Al[32][136];  // bf16 wx tile (overlaid: red)
    __shared__ float bias[G_];
    __shared__ float aw_s[T_];
    __shared__ float a_s[N_];
    __shared__ float wred[4];
    const int tid = threadIdx.x;
    const int b = blockIdx.x;

    for (int q = tid; q < G_ * 32; q += 256) {
        int r = q >> 5, c4 = (q & 31) << 2;
        float4 v = *(const float4*)(W_ih + r * N_ + c4);
        Wl[r][c4 + 0] = f2bf(v.x); Wl[r][c4 + 1] = f2bf(v.y);
        Wl[r][c4 + 2] = f2bf(v.z); Wl[r][c4 + 3] = f2bf(v.w);
    }
    bias[tid] = b_ih[tid] + b_hh[tid];
    aw_s[tid] = attn_w[2 * H_ + tid];
    __syncthreads();

    // ---- Phase A: attention softmax (shift-invariance kills h/c/bias) ----
    float (*red)[128] = (float(*)[128])&Al[0][0];
    const int n0 = (tid & 31) << 2;
    const int tg = tid >> 5;
    const float* xb = x + (size_t)b * (T_ * N_);
    {
        float p0 = 0.f, p1 = 0.f, p2 = 0.f, p3 = 0.f;
        for (int t = tg; t < T_; t += 8) {
            float4 v = *(const float4*)(xb + t * N_ + n0);
            float w = aw_s[t];
            p0 += v.x * w; p1 += v.y * w; p2 += v.z * w; p3 += v.w * w;
        }
        red[tg][n0 + 0] = p0; red[tg][n0 + 1] = p1;
        red[tg][n0 + 2] = p2; red[tg][n0 + 3] = p3;
    }
    __syncthreads();
    {
        float s = 0.f;
        if (tid < 128) {
            #pragma unroll
            for (int g = 0; g < 8; ++g) s += red[g][tid];
        }
        float m = (tid < 128) ? s : -1e30f;
        #pragma unroll
        for (int d = 1; d < 64; d <<= 1) m = fmaxf(m, __shfl_xor(m, d));
        if ((tid & 63) == 0) wred[tid >> 6] = m;
        __syncthreads();
        m = fmaxf(wred[0], wred[1]);
        __syncthreads();
        float e = (tid < 128) ? __expf(s - m) : 0.f;
        float z = e;
        #pragma unroll
        for (int d = 1; d < 64; d <<= 1) z += __shfl_xor(z, d);
        if ((tid & 63) == 0) wred[tid >> 6] = z;
        __syncthreads();
        z = wred[0] + wred[1];
        if (tid < 128) a_s[tid] = e / z;
    }
    __syncthreads();

    // ---- Phase B: weighting + MFMA GEMM ----
    const int lane = tid & 63;
    const int lr = lane & 15;
    const int lk = (lane >> 4) << 3;
    const int gc0 = (tid >> 6) << 6;
    const int orow = (lane >> 4) << 2;

    for (int st = 0; st < 8; ++st) {
        const int r0 = b * T_ + st * 32;
        __syncthreads();
        for (int q = tid; q < 32 * 32; q += 256) {
            int r = q >> 5, c4 = (q & 31) << 2;
            size_t off = (size_t)(r0 + r) * N_ + c4;
            float4 v = *(const float4*)(x + off);
            float4 w;
            w.x = a_s[c4 + 0] * v.x; w.y = a_s[c4 + 1] * v.y;
            w.z = a_s[c4 + 2] * v.z; w.w = a_s[c4 + 3] * v.w;
            *(float4*)(iw + off) = w;            // output 0 (f32, exact)
            Al[r][c4 + 0] = f2bf(w.x); Al[r][c4 + 1] = f2bf(w.y);
            Al[r][c4 + 2] = f2bf(w.z); Al[r][c4 + 3] = f2bf(w.w);
        }
        __syncthreads();

        f32x4 acc[2][4];
        #pragma unroll
        for (int mt = 0; mt < 2; ++mt)
            #pragma unroll
            for (int nt = 0; nt < 4; ++nt)
                acc[mt][nt] = (f32x4){0.f, 0.f, 0.f, 0.f};

        #pragma unroll
        for (int kk = 0; kk < N_; kk += 32) {
            short8 af0 = *(const short8*)(&Al[lr][kk + lk]);
            short8 af1 = *(const short8*)(&Al[16 + lr][kk + lk]);
            #pragma unroll
            for (int nt = 0; nt < 4; ++nt) {
                short8 bfv = *(const short8*)(&Wl[gc0 + nt * 16 + lr][kk + lk]);
                acc[0][nt] = __builtin_amdgcn_mfma_f32_16x16x32_bf16(af0, bfv, acc[0][nt], 0, 0, 0);
                acc[1][nt] = __builtin_amdgcn_mfma_f32_16x16x32_bf16(af1, bfv, acc[1][nt], 0, 0, 0);
            }
        }
        // D: col = gc0+nt*16+lr (gate index), row = mt*16+(lane>>4)*4+reg
        #pragma unroll
        for (int mt = 0; mt < 2; ++mt) {
            #pragma unroll
            for (int nt = 0; nt < 4; ++nt) {
                int col = gc0 + nt * 16 + lr;
                float bs = bias[col];
                int cell = col & 63, qg = col >> 6;
                #pragma unroll
                for (int rg = 0; rg < 4; ++rg) {
                    int rr = r0 + mt * 16 + orow + rg;
                    gatesx[((size_t)rr * H_ + cell) * 4 + qg] =
                        (_Float16)(acc[mt][nt][rg] + bs);
                }
            }
        }
    }
}

// ---------------------------------------------------------------------------
// K3: LSTM recurrence, single-wave blocks (64 thr), 512 blocks, no barriers.
// Round-6 lesson: attribute/pin tricks do NOT stop the scheduler from sinking
// a 128-reg weight load+convert chain into the loop (VGPR_Count=120 < 128).
// This version loads PRE-PACKED f16 weights via asm volatile
// global_load_dwordx4: asm results cannot be rematerialized -> weights are
// structurally forced to stay register-resident. One 8B gate load per step.
// ---------------------------------------------------------------------------
__global__ __attribute__((amdgpu_flat_work_group_size(64, 64)))
__attribute__((amdgpu_waves_per_eu(1, 1)))
void k_rnn5(const _Float16* __restrict__ gatesx,
            const uint4* __restrict__ wpack,
            float* __restrict__ enc) {
    __shared__ __align__(16) _Float16 hb[H_];   // h_t, f16, 128 B
    const int j = threadIdx.x;   // cell index
    const int b = blockIdx.x;

    // 32 x dwordx4 = 128 VGPRs of packed half2 weights (4 gate rows x 32 h2)
    uint4 wv[4][8];
    #pragma unroll
    for (int g = 0; g < 4; ++g) {
        #pragma unroll
        for (int q = 0; q < 8; ++q) {
            unsigned voff = (unsigned)((((g << 3) + q) * 64 + j) << 4);
            asm volatile("global_load_dwordx4 %0, %1, %2"
                         : "=v"(wv[g][q]) : "v"(voff), "s"(wpack) : "memory");
        }
    }
    asm volatile("s_waitcnt vmcnt(0)" ::: "memory");

    if (j < 32) ((unsigned int*)hb)[j] = 0u;   // h_{-1} = 0
    __syncthreads();                            // single wave: ~free
    float c = 0.f;

    const _Float16* gx = gatesx + ((size_t)b * T_ * H_ + j) * 4;
    uint2 gcur = *(const uint2*)gx;            // [i,f,g,o] f16 quad, t=0

    for (int t = 0; t < T_; ++t) {
        // prefetch next step's gate quad (one coalesced 8B load)
        uint2 gnx = *(const uint2*)(gx + (size_t)(t + 1 < T_ ? t + 1 : t) * G_);

        half2_t gif = u2h2(gcur.x), ggo = u2h2(gcur.y);
        float a0 = (float)gif.x, a1 = (float)gif.y;
        float a2 = (float)ggo.x, a3 = (float)ggo.y;

        // h broadcast: 8 uniform-address b128 reads (bank-broadcast)
        const uint4* hv4 = (const uint4*)hb;
        #pragma unroll
        for (int q = 0; q < 8; ++q) {
            uint4 ch = hv4[q];
            a0 = __builtin_amdgcn_fdot2(u2h2(wv[0][q].x), u2h2(ch.x), a0, false);
            a1 = __builtin_amdgcn_fdot2(u2h2(wv[1][q].x), u2h2(ch.x), a1, false);
            a2 = __builtin_amdgcn_fdot2(u2h2(wv[2][q].x), u2h2(ch.x), a2, false);
            a3 = __builtin_amdgcn_fdot2(u2h2(wv[3][q].x), u2h2(ch.x), a3, false);
            a0 = __builtin_amdgcn_fdot2(u2h2(wv[0][q].y), u2h2(ch.y), a0, false);
            a1 = __builtin_amdgcn_fdot2(u2h2(wv[1][q].y), u2h2(ch.y), a1, false);
            a2 = __builtin_amdgcn_fdot2(u2h2(wv[2][q].y), u2h2(ch.y), a2, false);
            a3 = __builtin_amdgcn_fdot2(u2h2(wv[3][q].y), u2h2(ch.y), a3, false);
            a0 = __builtin_amdgcn_fdot2(u2h2(wv[0][q].z), u2h2(ch.z), a0, false);
            a1 = __builtin_amdgcn_fdot2(u2h2(wv[1][q].z), u2h2(ch.z), a1, false);
            a2 = __builtin_amdgcn_fdot2(u2h2(wv[2][q].z), u2h2(ch.z), a2, false);
            a3 = __builtin_amdgcn_fdot2(u2h2(wv[3][q].z), u2h2(ch.z), a3, false);
            a0 = __builtin_amdgcn_fdot2(u2h2(wv[0][q].w), u2h2(ch.w), a0, false);
            a1 = __builtin_amdgcn_fdot2(u2h2(wv[1][q].w), u2h2(ch.w), a1, false);
            a2 = __builtin_amdgcn_fdot2(u2h2(wv[2][q].w), u2h2(ch.w), a2, false);
            a3 = __builtin_amdgcn_fdot2(u2h2(wv[3][q].w), u2h2(ch.w), a3, false);
        }

        // cell math, fully lane-local (gate order i,f,g,o)
        float si = 1.f / (1.f + __expf(-a0));
        float sf = 1.f / (1.f + __expf(-a1));
        float tg = 1.f - 2.f / (__expf(2.f * a2) + 1.f);   // tanh(g)
        float so = 1.f / (1.f + __expf(-a3));
        c = sf * c + si * tg;
        float tc = 1.f - 2.f / (__expf(2.f * c) + 1.f);    // tanh(c)
        float h = so * tc;

        hb[j] = (_Float16)h;   // same-wave LDS ordering via lgkmcnt
        enc[((size_t)b * T_ + t) * H_ + j] = h;
        gcur = gnx;
    }
}

extern "C" void kernel_launch(void* const* d_in, const int* in_sizes, int n_in,
                              void* d_out, int out_size, void* d_ws, size_t ws_size,
                              hipStream_t stream) {
    if (n_in < 7 || in_sizes[0] != B_ * T_ * N_) return;

    const float* x    = (const float*)d_in[0];
    const float* aw   = (const float*)d_in[1];
    // d_in[2] (attn_b) provably cancels in the softmax — unused.
    const float* W_ih = (const float*)d_in[3];
    const float* W_hh = (const float*)d_in[4];
    const float* b_ih = (const float*)d_in[5];
    const float* b_hh = (const float*)d_in[6];

    float* iwp = (float*)d_out;                          // (B,T,N) f32
    float* enc = (float*)d_out + (size_t)B_ * T_ * N_;   // (B,T,H) f32

    size_t gx_bytes = (size_t)B_ * T_ * G_ * sizeof(_Float16);   // 33.5 MB
    _Float16* gatesx = (_Float16*)d_ws;
    uint4* wpack = (uint4*)((char*)d_ws + gx_bytes);             // 32 KB
    size_t need = gx_bytes + 2048 * sizeof(uint4);
    if (ws_size < need) return;  // fail loudly rather than corrupt

    hipLaunchKernelGGL(k_wpack, dim3(8), dim3(256), 0, stream, W_hh, wpack);
    hipLaunchKernelGGL(k_awgemm, dim3(B_), dim3(256), 0, stream,
                       x, aw, W_ih, b_ih, b_hh, iwp, gatesx);
    hipLaunchKernelGGL(k_rnn5, dim3(B_), dim3(64), 0, stream, gatesx, wpack, enc);
}

// Round 8
// 190.283 us; speedup vs baseline: 1.1530x; 1.0958x over previous
//
#include <hip/hip_runtime.h>
#include <hip/hip_fp16.h>
#include <cstdint>
#include <cstddef>

#define B_ 512
#define T_ 256
#define N_ 128
#define H_ 64
#define G_ 256  // 4H

typedef __attribute__((ext_vector_type(8))) short short8;
typedef __attribute__((ext_vector_type(4))) float f32x4;
typedef _Float16 half2_t __attribute__((ext_vector_type(2)));

static __device__ __forceinline__ unsigned short f2bf(float f) {
    union { float f; unsigned int i; } v;
    v.f = f;
    unsigned int x = v.i;
    return (unsigned short)((x + 0x7fffu + ((x >> 16) & 1u)) >> 16);  // RNE
}
static __device__ __forceinline__ half2_t u2h2(unsigned int u) {
    union { unsigned int u; half2_t h; } v; v.u = u; return v.h;
}

// ---------------------------------------------------------------------------
// K0: pack W_hh (f32 [4H][H]) -> wpack uint4 [4][8][64]: wpack[g][q][j] =
// half2x4 of W_hh[g*64+j][8q..8q+7].  Exactly the per-lane order k_rnn6 loads.
// ---------------------------------------------------------------------------
__global__ __launch_bounds__(256) void k_wpack(const float* __restrict__ W_hh,
                                               uint4* __restrict__ wpack) {
    int idx = blockIdx.x * 256 + threadIdx.x;   // 2048 entries
    if (idx >= 2048) return;
    int g = idx >> 9, q = (idx >> 6) & 7, j = idx & 63;
    const float* src = W_hh + ((size_t)(g * H_ + j)) * H_ + q * 8;
    float4 a = *(const float4*)(src);
    float4 b = *(const float4*)(src + 4);
    union { uint4 u; half2_t h[4]; } pk;
    pk.h[0] = (half2_t){(_Float16)a.x, (_Float16)a.y};
    pk.h[1] = (half2_t){(_Float16)a.z, (_Float16)a.w};
    pk.h[2] = (half2_t){(_Float16)b.x, (_Float16)b.y};
    pk.h[3] = (half2_t){(_Float16)b.z, (_Float16)b.w};
    wpack[idx] = pk.u;
}

// ---------------------------------------------------------------------------
// K1+K2 fused (round-5 form, unchanged: 80.9 KB LDS, 2 blocks/CU).
// Phase A: a[n] = softmax_n( sum_t x[b][t][n]*aw2[t] )
// Phase B: iw = a*x (f32, exact) -> d_out; gatesx -> ws as f16 in
//          [b][t][cell][gate i,f,g,o] quads (one 8B load/step in k_rnn6).
// ---------------------------------------------------------------------------
__global__ __launch_bounds__(256) void k_awgemm(const float* __restrict__ x,
                                                const float* __restrict__ attn_w,
                                                const float* __restrict__ W_ih,
                                                const float* __restrict__ b_ih,
                                                const float* __restrict__ b_hh,
                                                float* __restrict__ iw,
                                                _Float16* __restrict__ gatesx) {
    __shared__ __align__(16) unsigned short Wl[G_][136];  // bf16 W_ih, padded
    __shared__ __align__(16) unsigned short Al[32][136];  // bf16 wx tile (overlaid: red)
    __shared__ float bias[G_];
    __shared__ float aw_s[T_];
    __shared__ float a_s[N_];
    __shared__ float wred[4];
    const int tid = threadIdx.x;
    const int b = blockIdx.x;

    for (int q = tid; q < G_ * 32; q += 256) {
        int r = q >> 5, c4 = (q & 31) << 2;
        float4 v = *(const float4*)(W_ih + r * N_ + c4);
        Wl[r][c4 + 0] = f2bf(v.x); Wl[r][c4 + 1] = f2bf(v.y);
        Wl[r][c4 + 2] = f2bf(v.z); Wl[r][c4 + 3] = f2bf(v.w);
    }
    bias[tid] = b_ih[tid] + b_hh[tid];
    aw_s[tid] = attn_w[2 * H_ + tid];
    __syncthreads();

    // ---- Phase A: attention softmax (shift-invariance kills h/c/bias) ----
    float (*red)[128] = (float(*)[128])&Al[0][0];
    const int n0 = (tid & 31) << 2;
    const int tg = tid >> 5;
    const float* xb = x + (size_t)b * (T_ * N_);
    {
        float p0 = 0.f, p1 = 0.f, p2 = 0.f, p3 = 0.f;
        for (int t = tg; t < T_; t += 8) {
            float4 v = *(const float4*)(xb + t * N_ + n0);
            float w = aw_s[t];
            p0 += v.x * w; p1 += v.y * w; p2 += v.z * w; p3 += v.w * w;
        }
        red[tg][n0 + 0] = p0; red[tg][n0 + 1] = p1;
        red[tg][n0 + 2] = p2; red[tg][n0 + 3] = p3;
    }
    __syncthreads();
    {
        float s = 0.f;
        if (tid < 128) {
            #pragma unroll
            for (int g = 0; g < 8; ++g) s += red[g][tid];
        }
        float m = (tid < 128) ? s : -1e30f;
        #pragma unroll
        for (int d = 1; d < 64; d <<= 1) m = fmaxf(m, __shfl_xor(m, d));
        if ((tid & 63) == 0) wred[tid >> 6] = m;
        __syncthreads();
        m = fmaxf(wred[0], wred[1]);
        __syncthreads();
        float e = (tid < 128) ? __expf(s - m) : 0.f;
        float z = e;
        #pragma unroll
        for (int d = 1; d < 64; d <<= 1) z += __shfl_xor(z, d);
        if ((tid & 63) == 0) wred[tid >> 6] = z;
        __syncthreads();
        z = wred[0] + wred[1];
        if (tid < 128) a_s[tid] = e / z;
    }
    __syncthreads();

    // ---- Phase B: weighting + MFMA GEMM ----
    const int lane = tid & 63;
    const int lr = lane & 15;
    const int lk = (lane >> 4) << 3;
    const int gc0 = (tid >> 6) << 6;
    const int orow = (lane >> 4) << 2;

    for (int st = 0; st < 8; ++st) {
        const int r0 = b * T_ + st * 32;
        __syncthreads();
        for (int q = tid; q < 32 * 32; q += 256) {
            int r = q >> 5, c4 = (q & 31) << 2;
            size_t off = (size_t)(r0 + r) * N_ + c4;
            float4 v = *(const float4*)(x + off);
            float4 w;
            w.x = a_s[c4 + 0] * v.x; w.y = a_s[c4 + 1] * v.y;
            w.z = a_s[c4 + 2] * v.z; w.w = a_s[c4 + 3] * v.w;
            *(float4*)(iw + off) = w;            // output 0 (f32, exact)
            Al[r][c4 + 0] = f2bf(w.x); Al[r][c4 + 1] = f2bf(w.y);
            Al[r][c4 + 2] = f2bf(w.z); Al[r][c4 + 3] = f2bf(w.w);
        }
        __syncthreads();

        f32x4 acc[2][4];
        #pragma unroll
        for (int mt = 0; mt < 2; ++mt)
            #pragma unroll
            for (int nt = 0; nt < 4; ++nt)
                acc[mt][nt] = (f32x4){0.f, 0.f, 0.f, 0.f};

        #pragma unroll
        for (int kk = 0; kk < N_; kk += 32) {
            short8 af0 = *(const short8*)(&Al[lr][kk + lk]);
            short8 af1 = *(const short8*)(&Al[16 + lr][kk + lk]);
            #pragma unroll
            for (int nt = 0; nt < 4; ++nt) {
                short8 bfv = *(const short8*)(&Wl[gc0 + nt * 16 + lr][kk + lk]);
                acc[0][nt] = __builtin_amdgcn_mfma_f32_16x16x32_bf16(af0, bfv, acc[0][nt], 0, 0, 0);
                acc[1][nt] = __builtin_amdgcn_mfma_f32_16x16x32_bf16(af1, bfv, acc[1][nt], 0, 0, 0);
            }
        }
        // D: col = gc0+nt*16+lr (gate index), row = mt*16+(lane>>4)*4+reg
        #pragma unroll
        for (int mt = 0; mt < 2; ++mt) {
            #pragma unroll
            for (int nt = 0; nt < 4; ++nt) {
                int col = gc0 + nt * 16 + lr;
                float bs = bias[col];
                int cell = col & 63, qg = col >> 6;
                #pragma unroll
                for (int rg = 0; rg < 4; ++rg) {
                    int rr = r0 + mt * 16 + orow + rg;
                    gatesx[((size_t)rr * H_ + cell) * 4 + qg] =
                        (_Float16)(acc[mt][nt][rg] + bs);
                }
            }
        }
    }
}

// ---------------------------------------------------------------------------
// K3: LSTM recurrence, single-wave blocks, ZERO LDS, zero barriers.
// Round-7: weights resident (asm loads, VGPR=132) but still 1453 cy/step --
// ~800 cy unexplained stall. Suspects: depth-1 gate prefetch sinkable to the
// loop bottom (exposes ~900cy HBM latency), and the LDS h round-trip.
// This version:
//  - depth-2 prefetch with NAMED reg rotation (g0,g1,g2): even bottom-sunk
//    loads get a full iteration of slack.
//  - h broadcast WITHOUT LDS: v_cvt_f16_f32 + DPP quad_perm(1,0,3,2) packs
//    (h[2m],h[2m+1]) into every lane-pair; 32x v_readlane -> SGPR; fdot2
//    takes the SGPR operand directly (1 sgpr/VALU-inst is legal).
// ---------------------------------------------------------------------------
__global__ __attribute__((amdgpu_flat_work_group_size(64, 64)))
__attribute__((amdgpu_waves_per_eu(1, 1)))
void k_rnn6(const _Float16* __restrict__ gatesx,
            const uint4* __restrict__ wpack,
            float* __restrict__ enc) {
    const int j = threadIdx.x;   // cell index
    const int b = blockIdx.x;

    // 32 x dwordx4 = 128 VGPRs of packed half2 weights (4 gate rows x 8 quads)
    uint4 wv[4][8];
    #pragma unroll
    for (int g = 0; g < 4; ++g) {
        #pragma unroll
        for (int q = 0; q < 8; ++q) {
            unsigned voff = (unsigned)((((g << 3) + q) * 64 + j) << 4);
            asm volatile("global_load_dwordx4 %0, %1, %2"
                         : "=v"(wv[g][q]) : "v"(voff), "s"(wpack) : "memory");
        }
    }
    asm volatile("s_waitcnt vmcnt(0)" ::: "memory");

    float c = 0.f;
    unsigned hpk = 0u;                 // lane-pair packed f16 (h[2m], h[2m+1]); h_{-1}=0
    const bool even = ((j & 1) == 0);

    const _Float16* gx = gatesx + ((size_t)b * T_ * H_ + j) * 4;
    uint2 g0 = *(const uint2*)(gx);            // t = 0
    uint2 g1 = *(const uint2*)(gx + G_);       // t = 1
    const _Float16* gpre = gx + 2 * (size_t)G_;
    float* ep = enc + (size_t)b * T_ * H_ + j;

    for (int t = 0; t < T_; ++t) {
        uint2 g2 = *(const uint2*)(gpre);      // t+2 (clamped)
        if (t + 3 < T_) gpre += G_;

        half2_t gif = u2h2(g0.x), ggo = u2h2(g0.y);
        float a0 = (float)gif.x, a1 = (float)gif.y;
        float a2 = (float)ggo.x, a3 = (float)ggo.y;

        // h broadcast via readlane: s = hpk[lane 2m] = (h[8q+2c], h[8q+2c+1])
#define DOT_STEP(m, c0, c1, c2, c3)                                         \
        do {                                                                \
            unsigned hs_ = (unsigned)__builtin_amdgcn_readlane((int)hpk, 2 * (m)); \
            half2_t hh_ = u2h2(hs_);                                        \
            a0 = __builtin_amdgcn_fdot2(u2h2(c0), hh_, a0, false);          \
            a1 = __builtin_amdgcn_fdot2(u2h2(c1), hh_, a1, false);          \
            a2 = __builtin_amdgcn_fdot2(u2h2(c2), hh_, a2, false);          \
            a3 = __builtin_amdgcn_fdot2(u2h2(c3), hh_, a3, false);          \
        } while (0)

        #pragma unroll
        for (int q = 0; q < 8; ++q) {
            DOT_STEP(4 * q + 0, wv[0][q].x, wv[1][q].x, wv[2][q].x, wv[3][q].x);
            DOT_STEP(4 * q + 1, wv[0][q].y, wv[1][q].y, wv[2][q].y, wv[3][q].y);
            DOT_STEP(4 * q + 2, wv[0][q].z, wv[1][q].z, wv[2][q].z, wv[3][q].z);
            DOT_STEP(4 * q + 3, wv[0][q].w, wv[1][q].w, wv[2][q].w, wv[3][q].w);
        }
#undef DOT_STEP

        // cell math, fully lane-local (gate order i,f,g,o)
        float si = 1.f / (1.f + __expf(-a0));
        float sf = 1.f / (1.f + __expf(-a1));
        float tg = 1.f - 2.f / (__expf(2.f * a2) + 1.f);   // tanh(g)
        float so = 1.f / (1.f + __expf(-a3));
        c = sf * c + si * tg;
        float tc = 1.f - 2.f / (__expf(2.f * c) + 1.f);    // tanh(c)
        float h = so * tc;

        // pack (h[2m], h[2m+1]) into every lane of the pair via DPP swap
        union { _Float16 hf; unsigned short u; } cv; cv.hf = (_Float16)h;
        unsigned hf = cv.u;
        unsigned nb = (unsigned)__builtin_amdgcn_mov_dpp((int)hf, 0xB1, 0xF, 0xF, true);
        hpk = even ? (hf | (nb << 16)) : (nb | (hf << 16));

        *ep = h;                 // enc (f32) — off-chain store
        ep += H_;
        g0 = g1; g1 = g2;
    }
}

extern "C" void kernel_launch(void* const* d_in, const int* in_sizes, int n_in,
                              void* d_out, int out_size, void* d_ws, size_t ws_size,
                              hipStream_t stream) {
    if (n_in < 7 || in_sizes[0] != B_ * T_ * N_) return;

    const float* x    = (const float*)d_in[0];
    const float* aw   = (const float*)d_in[1];
    // d_in[2] (attn_b) provably cancels in the softmax — unused.
    const float* W_ih = (const float*)d_in[3];
    const float* W_hh = (const float*)d_in[4];
    const float* b_ih = (const float*)d_in[5];
    const float* b_hh = (const float*)d_in[6];

    float* iwp = (float*)d_out;                          // (B,T,N) f32
    float* enc = (float*)d_out + (size_t)B_ * T_ * N_;   // (B,T,H) f32

    size_t gx_bytes = (size_t)B_ * T_ * G_ * sizeof(_Float16);   // 33.5 MB
    _Float16* gatesx = (_Float16*)d_ws;
    uint4* wpack = (uint4*)((char*)d_ws + gx_bytes);             // 32 KB
    size_t need = gx_bytes + 2048 * sizeof(uint4);
    if (ws_size < need) return;  // fail loudly rather than corrupt

    hipLaunchKernelGGL(k_wpack, dim3(8), dim3(256), 0, stream, W_hh, wpack);
    hipLaunchKernelGGL(k_awgemm, dim3(B_), dim3(256), 0, stream,
                       x, aw, W_ih, b_ih, b_hh, iwp, gatesx);
    hipLaunchKernelGGL(k_rnn6, dim3(B_), dim3(64), 0, stream, gatesx, wpack, enc);
}

// Round 9
// 186.992 us; speedup vs baseline: 1.1733x; 1.0176x over previous
//
#include <hip/hip_runtime.h>
#include <hip/hip_fp16.h>
#include <cstdint>
#include <cstddef>

#define B_ 512
#define T_ 256
#define N_ 128
#define H_ 64
#define G_ 256  // 4H

typedef __attribute__((ext_vector_type(8))) short short8;
typedef __attribute__((ext_vector_type(4))) float f32x4;
typedef _Float16 half2_t __attribute__((ext_vector_type(2)));

static __device__ __forceinline__ unsigned short f2bf(float f) {
    union { float f; unsigned int i; } v;
    v.f = f;
    unsigned int x = v.i;
    return (unsigned short)((x + 0x7fffu + ((x >> 16) & 1u)) >> 16);  // RNE
}
static __device__ __forceinline__ half2_t u2h2(unsigned int u) {
    union { unsigned int u; half2_t h; } v; v.u = u; return v.h;
}

// ---------------------------------------------------------------------------
// K0: pack W_hh (f32 [4H][H]) -> wpack uint4 [4][8][64]: wpack[g][q][j] =
// half2x4 of W_hh[g*64+j][8q..8q+7].  Exactly the per-lane order k_rnn7 loads.
// ---------------------------------------------------------------------------
__global__ __launch_bounds__(256) void k_wpack(const float* __restrict__ W_hh,
                                               uint4* __restrict__ wpack) {
    int idx = blockIdx.x * 256 + threadIdx.x;   // 2048 entries
    if (idx >= 2048) return;
    int g = idx >> 9, q = (idx >> 6) & 7, j = idx & 63;
    const float* src = W_hh + ((size_t)(g * H_ + j)) * H_ + q * 8;
    float4 a = *(const float4*)(src);
    float4 b = *(const float4*)(src + 4);
    union { uint4 u; half2_t h[4]; } pk;
    pk.h[0] = (half2_t){(_Float16)a.x, (_Float16)a.y};
    pk.h[1] = (half2_t){(_Float16)a.z, (_Float16)a.w};
    pk.h[2] = (half2_t){(_Float16)b.x, (_Float16)b.y};
    pk.h[3] = (half2_t){(_Float16)b.z, (_Float16)b.w};
    wpack[idx] = pk.u;
}

// ---------------------------------------------------------------------------
// K1+K2 fused (unchanged this round: ~50us, BW floor ~37us — next target).
// Phase A: a[n] = softmax_n( sum_t x[b][t][n]*aw2[t] )
// Phase B: iw = a*x (f32, exact) -> d_out; gatesx -> ws as f16 in
//          [b][t][cell][gate i,f,g,o] quads (one 8B load/step in k_rnn7).
// ---------------------------------------------------------------------------
__global__ __launch_bounds__(256) void k_awgemm(const float* __restrict__ x,
                                                const float* __restrict__ attn_w,
                                                const float* __restrict__ W_ih,
                                                const float* __restrict__ b_ih,
                                                const float* __restrict__ b_hh,
                                                float* __restrict__ iw,
                                                _Float16* __restrict__ gatesx) {
    __shared__ __align__(16) unsigned short Wl[G_][136];  // bf16 W_ih, padded
    __shared__ __align__(16) unsigned short Al[32][136];  // bf16 wx tile (overlaid: red)
    __shared__ float bias[G_];
    __shared__ float aw_s[T_];
    __shared__ float a_s[N_];
    __shared__ float wred[4];
    const int tid = threadIdx.x;
    const int b = blockIdx.x;

    for (int q = tid; q < G_ * 32; q += 256) {
        int r = q >> 5, c4 = (q & 31) << 2;
        float4 v = *(const float4*)(W_ih + r * N_ + c4);
        Wl[r][c4 + 0] = f2bf(v.x); Wl[r][c4 + 1] = f2bf(v.y);
        Wl[r][c4 + 2] = f2bf(v.z); Wl[r][c4 + 3] = f2bf(v.w);
    }
    bias[tid] = b_ih[tid] + b_hh[tid];
    aw_s[tid] = attn_w[2 * H_ + tid];
    __syncthreads();

    // ---- Phase A: attention softmax (shift-invariance kills h/c/bias) ----
    float (*red)[128] = (float(*)[128])&Al[0][0];
    const int n0 = (tid & 31) << 2;
    const int tg = tid >> 5;
    const float* xb = x + (size_t)b * (T_ * N_);
    {
        float p0 = 0.f, p1 = 0.f, p2 = 0.f, p3 = 0.f;
        for (int t = tg; t < T_; t += 8) {
            float4 v = *(const float4*)(xb + t * N_ + n0);
            float w = aw_s[t];
            p0 += v.x * w; p1 += v.y * w; p2 += v.z * w; p3 += v.w * w;
        }
        red[tg][n0 + 0] = p0; red[tg][n0 + 1] = p1;
        red[tg][n0 + 2] = p2; red[tg][n0 + 3] = p3;
    }
    __syncthreads();
    {
        float s = 0.f;
        if (tid < 128) {
            #pragma unroll
            for (int g = 0; g < 8; ++g) s += red[g][tid];
        }
        float m = (tid < 128) ? s : -1e30f;
        #pragma unroll
        for (int d = 1; d < 64; d <<= 1) m = fmaxf(m, __shfl_xor(m, d));
        if ((tid & 63) == 0) wred[tid >> 6] = m;
        __syncthreads();
        m = fmaxf(wred[0], wred[1]);
        __syncthreads();
        float e = (tid < 128) ? __expf(s - m) : 0.f;
        float z = e;
        #pragma unroll
        for (int d = 1; d < 64; d <<= 1) z += __shfl_xor(z, d);
        if ((tid & 63) == 0) wred[tid >> 6] = z;
        __syncthreads();
        z = wred[0] + wred[1];
        if (tid < 128) a_s[tid] = e / z;
    }
    __syncthreads();

    // ---- Phase B: weighting + MFMA GEMM ----
    const int lane = tid & 63;
    const int lr = lane & 15;
    const int lk = (lane >> 4) << 3;
    const int gc0 = (tid >> 6) << 6;
    const int orow = (lane >> 4) << 2;

    for (int st = 0; st < 8; ++st) {
        const int r0 = b * T_ + st * 32;
        __syncthreads();
        for (int q = tid; q < 32 * 32; q += 256) {
            int r = q >> 5, c4 = (q & 31) << 2;
            size_t off = (size_t)(r0 + r) * N_ + c4;
            float4 v = *(const float4*)(x + off);
            float4 w;
            w.x = a_s[c4 + 0] * v.x; w.y = a_s[c4 + 1] * v.y;
            w.z = a_s[c4 + 2] * v.z; w.w = a_s[c4 + 3] * v.w;
            *(float4*)(iw + off) = w;            // output 0 (f32, exact)
            Al[r][c4 + 0] = f2bf(w.x); Al[r][c4 + 1] = f2bf(w.y);
            Al[r][c4 + 2] = f2bf(w.z); Al[r][c4 + 3] = f2bf(w.w);
        }
        __syncthreads();

        f32x4 acc[2][4];
        #pragma unroll
        for (int mt = 0; mt < 2; ++mt)
            #pragma unroll
            for (int nt = 0; nt < 4; ++nt)
                acc[mt][nt] = (f32x4){0.f, 0.f, 0.f, 0.f};

        #pragma unroll
        for (int kk = 0; kk < N_; kk += 32) {
            short8 af0 = *(const short8*)(&Al[lr][kk + lk]);
            short8 af1 = *(const short8*)(&Al[16 + lr][kk + lk]);
            #pragma unroll
            for (int nt = 0; nt < 4; ++nt) {
                short8 bfv = *(const short8*)(&Wl[gc0 + nt * 16 + lr][kk + lk]);
                acc[0][nt] = __builtin_amdgcn_mfma_f32_16x16x32_bf16(af0, bfv, acc[0][nt], 0, 0, 0);
                acc[1][nt] = __builtin_amdgcn_mfma_f32_16x16x32_bf16(af1, bfv, acc[1][nt], 0, 0, 0);
            }
        }
        // D: col = gc0+nt*16+lr (gate index), row = mt*16+(lane>>4)*4+reg
        #pragma unroll
        for (int mt = 0; mt < 2; ++mt) {
            #pragma unroll
            for (int nt = 0; nt < 4; ++nt) {
                int col = gc0 + nt * 16 + lr;
                float bs = bias[col];
                int cell = col & 63, qg = col >> 6;
                #pragma unroll
                for (int rg = 0; rg < 4; ++rg) {
                    int rr = r0 + mt * 16 + orow + rg;
                    gatesx[((size_t)rr * H_ + cell) * 4 + qg] =
                        (_Float16)(acc[mt][nt][rg] + bs);
                }
            }
        }
    }
}

// ---------------------------------------------------------------------------
// K3: LSTM recurrence, single-wave blocks, zero LDS/barriers.
// Round-8 lesson: register ROTATION (g0=g1;g1=g2) forces the t+2 load's
// s_waitcnt into the SAME iteration (the move needs the value) -> ~500cy of
// exposed HBM latency per step. Fix: unroll x2 with NAMED gA/gB, no moves;
// each reload issues right after its old value dies (top of the half-step)
// and is next used a full unrolled iteration later.
// ---------------------------------------------------------------------------
__global__ __attribute__((amdgpu_flat_work_group_size(64, 64)))
__attribute__((amdgpu_waves_per_eu(1, 1)))
void k_rnn7(const _Float16* __restrict__ gatesx,
            const uint4* __restrict__ wpack,
            float* __restrict__ enc) {
    const int j = threadIdx.x;   // cell index
    const int b = blockIdx.x;

    // 32 x dwordx4 = 128 VGPRs of packed half2 weights (4 gate rows x 8 quads)
    uint4 wv[4][8];
    #pragma unroll
    for (int g = 0; g < 4; ++g) {
        #pragma unroll
        for (int q = 0; q < 8; ++q) {
            unsigned voff = (unsigned)((((g << 3) + q) * 64 + j) << 4);
            asm volatile("global_load_dwordx4 %0, %1, %2"
                         : "=v"(wv[g][q]) : "v"(voff), "s"(wpack) : "memory");
        }
    }
    asm volatile("s_waitcnt vmcnt(0)" ::: "memory");

    float c = 0.f;
    unsigned hpk = 0u;                 // lane-pair packed f16 (h[2m], h[2m+1]); h_{-1}=0
    const bool even = ((j & 1) == 0);

    const _Float16* gx = gatesx + ((size_t)b * T_ * H_ + j) * 4;
    float* ep = enc + (size_t)b * T_ * H_ + j;

    uint2 gA = *(const uint2*)(gx);            // t = 0
    uint2 gB = *(const uint2*)(gx + G_);       // t = 1

#define DOT_STEP(m, c0, c1, c2, c3)                                         \
        do {                                                                \
            unsigned hs_ = (unsigned)__builtin_amdgcn_readlane((int)hpk, 2 * (m)); \
            half2_t hh_ = u2h2(hs_);                                        \
            a0 = __builtin_amdgcn_fdot2(u2h2(c0), hh_, a0, false);          \
            a1 = __builtin_amdgcn_fdot2(u2h2(c1), hh_, a1, false);          \
            a2 = __builtin_amdgcn_fdot2(u2h2(c2), hh_, a2, false);          \
            a3 = __builtin_amdgcn_fdot2(u2h2(c3), hh_, a3, false);          \
        } while (0)

    // one LSTM step: consumes GREG at the top (then GREG is dead), reloads
    // GREG for step TNEXT immediately (branchless clamped addr) -> the
    // waitcnt for the reload lands one full unrolled iteration later.
#define STEP(GREG, TNEXT)                                                   \
    {                                                                       \
        half2_t gif = u2h2(GREG.x), ggo = u2h2(GREG.y);                     \
        float a0 = (float)gif.x, a1 = (float)gif.y;                         \
        float a2 = (float)ggo.x, a3 = (float)ggo.y;                         \
        int tn_ = (TNEXT) < T_ ? (TNEXT) : (T_ - 1);                        \
        GREG = *(const uint2*)(gx + (size_t)tn_ * G_);                      \
        _Pragma("unroll")                                                   \
        for (int q = 0; q < 8; ++q) {                                       \
            DOT_STEP(4 * q + 0, wv[0][q].x, wv[1][q].x, wv[2][q].x, wv[3][q].x); \
            DOT_STEP(4 * q + 1, wv[0][q].y, wv[1][q].y, wv[2][q].y, wv[3][q].y); \
            DOT_STEP(4 * q + 2, wv[0][q].z, wv[1][q].z, wv[2][q].z, wv[3][q].z); \
            DOT_STEP(4 * q + 3, wv[0][q].w, wv[1][q].w, wv[2][q].w, wv[3][q].w); \
        }                                                                   \
        float si = 1.f / (1.f + __expf(-a0));                               \
        float sf = 1.f / (1.f + __expf(-a1));                               \
        float tg = 1.f - 2.f / (__expf(2.f * a2) + 1.f);                    \
        float so = 1.f / (1.f + __expf(-a3));                               \
        c = sf * c + si * tg;                                               \
        float tc = 1.f - 2.f / (__expf(2.f * c) + 1.f);                     \
        float h = so * tc;                                                  \
        union { _Float16 hf; unsigned short u; } cv_; cv_.hf = (_Float16)h; \
        unsigned hf_ = cv_.u;                                               \
        unsigned nb_ = (unsigned)__builtin_amdgcn_mov_dpp((int)hf_, 0xB1, 0xF, 0xF, true); \
        hpk = even ? (hf_ | (nb_ << 16)) : (nb_ | (hf_ << 16));             \
        *ep = h;                                                            \
        ep += H_;                                                           \
    }

    for (int t = 0; t < T_; t += 2) {
        STEP(gA, t + 2);
        STEP(gB, t + 3);
    }
#undef STEP
#undef DOT_STEP
}

extern "C" void kernel_launch(void* const* d_in, const int* in_sizes, int n_in,
                              void* d_out, int out_size, void* d_ws, size_t ws_size,
                              hipStream_t stream) {
    if (n_in < 7 || in_sizes[0] != B_ * T_ * N_) return;

    const float* x    = (const float*)d_in[0];
    const float* aw   = (const float*)d_in[1];
    // d_in[2] (attn_b) provably cancels in the softmax — unused.
    const float* W_ih = (const float*)d_in[3];
    const float* W_hh = (const float*)d_in[4];
    const float* b_ih = (const float*)d_in[5];
    const float* b_hh = (const float*)d_in[6];

    float* iwp = (float*)d_out;                          // (B,T,N) f32
    float* enc = (float*)d_out + (size_t)B_ * T_ * N_;   // (B,T,H) f32

    size_t gx_bytes = (size_t)B_ * T_ * G_ * sizeof(_Float16);   // 33.5 MB
    _Float16* gatesx = (_Float16*)d_ws;
    uint4* wpack = (uint4*)((char*)d_ws + gx_bytes);             // 32 KB
    size_t need = gx_bytes + 2048 * sizeof(uint4);
    if (ws_size < need) return;  // fail loudly rather than corrupt

    hipLaunchKernelGGL(k_wpack, dim3(8), dim3(256), 0, stream, W_hh, wpack);
    hipLaunchKernelGGL(k_awgemm, dim3(B_), dim3(256), 0, stream,
                       x, aw, W_ih, b_ih, b_hh, iwp, gatesx);
    hipLaunchKernelGGL(k_rnn7, dim3(B_), dim3(64), 0, stream, gatesx, wpack, enc);
}